// Round 11
// baseline (795.680 us; speedup 1.0000x reference)
//
#include <hip/hip_runtime.h>

// SNN 4-layer LIF, T=25, B=256 — batched-time formulation.
// GEMMs for all 25 t at once (M=6400): i8 digit planes, i32 MFMA accum
// (exact), fp64 reconstruct. Sequential part = elementwise membrane scans
// (1 elem/thread). gemm23: 8 waves, each wave 1mt x 2nt (acc 128 VGPR),
// W double-buffered in LDS (2x64 KB) with register prefetch issued before
// the barrier — NO launch_bounds VGPR cap (r9 lesson: the (512,4) cap
// caused spills; the dbuf structure itself was correct).
// Layer 4 = exact-i8. nt-pair stays the fast blockIdx dim (XCD = blk%8
// pins each 2MB W-slice to one XCD L2, measured r4/r7).
// cur crosses kernels as f32 + f32 residual (res lives in the m-region of
// d_out until the scan overwrites it with m).

typedef int v4i  __attribute__((ext_vector_type(4)));
typedef int v16i __attribute__((ext_vector_type(16)));

#define T_   25
#define BB   256
#define DIN  768
#define HH   2048
#define PT   (BB*HH)
#define PT4  (BB*10)

// ---------------- digit decomposition (verified r5-r10) ----------------
// W[NROWS][K] -> NDIG planes @2^QSH, B-swizzled [ntile][kc(KC)][pl][lane][16]
template<int NDIG, int QSH, int KC>
__device__ __forceinline__
void decomp_w_one(const float* __restrict__ W, char* __restrict__ wpl, int K, int id)
{
    int n = id / (KC * 2), rem = id % (KC * 2);
    int kc = rem >> 1, h = rem & 1;
    const float* src = W + (size_t)n * K + kc * 32 + h * 16;
    const double scale = (double)(1ULL << QSH);
    alignas(16) char dig[NDIG][16];
#pragma unroll
    for (int e = 0; e < 16; ++e) {
        long long V = llround((double)src[e] * scale);
#pragma unroll
        for (int p = 0; p < NDIG - 1; ++p) {
            int d = (int)(V & 255); if (d >= 128) d -= 256;
            dig[p][e] = (char)d; V = (V - d) >> 8;
        }
        dig[NDIG - 1][e] = (char)V;
    }
    size_t base = (((size_t)(n >> 5) * KC + kc) * NDIG) * 1024 + (size_t)(h * 32 + (n & 31)) * 16;
#pragma unroll
    for (int p = 0; p < NDIG; ++p)
        *(int4*)(wpl + base + (size_t)p * 1024) = *(const int4*)dig[p];
}

// one dispatch: x (4pl @2^28, A-swizzled) + W1 + W2 + W3 + W4 (4pl @2^35)
__global__ __launch_bounds__(256)
void k_decomp_all(const float* __restrict__ x,  char* __restrict__ xpl,
                  const float* __restrict__ W1, char* __restrict__ w1pl,
                  const float* __restrict__ W2, char* __restrict__ w2pl,
                  const float* __restrict__ W3, char* __restrict__ w3pl,
                  const float* __restrict__ W4, char* __restrict__ w4pl)
{
    int gid = blockIdx.x * 256 + threadIdx.x;   // 931072 total = 3637*256
    if (gid < 307200) {                          // x: 6400 rows * 48
        int r = gid / 48, rem = gid % 48;
        int kc = rem >> 1, h = rem & 1;
        int t = r >> 8, b = r & 255;
        const float* src = x + ((size_t)b * T_ + t) * DIN + kc * 32 + h * 16;
        alignas(16) char dig[4][16];
#pragma unroll
        for (int e = 0; e < 16; ++e) {
            long long V = llround((double)src[e] * 268435456.0);  // 2^28
#pragma unroll
            for (int p = 0; p < 3; ++p) {
                int d = (int)(V & 255); if (d >= 128) d -= 256;
                dig[p][e] = (char)d; V = (V - d) >> 8;
            }
            dig[3][e] = (char)V;
        }
        size_t base = (((size_t)(r >> 5) * 24 + kc) * 4) * 1024 + (size_t)(h * 32 + (r & 31)) * 16;
#pragma unroll
        for (int p = 0; p < 4; ++p)
            *(int4*)(xpl + base + (size_t)p * 1024) = *(const int4*)dig[p];
        return;
    }
    gid -= 307200;
    if (gid < 98304)  { decomp_w_one<4,35,24>(W1, w1pl, 768,  gid); return; }
    gid -= 98304;
    if (gid < 262144) { decomp_w_one<4,35,64>(W2, w2pl, 2048, gid); return; }
    gid -= 262144;
    if (gid < 262144) { decomp_w_one<4,35,64>(W3, w3pl, 2048, gid); return; }
    gid -= 262144;
    if (gid < 1280)   { decomp_w_one<4,35,64>(W4, w4pl, 2048, gid); return; }
}

// ---------------- GEMM1: c1[6400][2048] = x(4pl) @ W1(4pl)^T + b1 ----------------
// 13 digit pairs s>=2 (verified r5-r10). 8 waves/block, W chunk in LDS (r8 form).
__global__ __launch_bounds__(512)
void k_gemm1(const char* __restrict__ xpl, const char* __restrict__ wpl,
             const float* __restrict__ bias, float* __restrict__ c_out,
             float* __restrict__ res_out)
{
    __shared__ char wlds[32768];
    int tid = threadIdx.x;
    int wm = tid >> 6, l = tid & 63;
    int nt = blockIdx.x;               // 0..63 (fast dim -> XCD = nt%8)
    int mt = blockIdx.y * 8 + wm;      // 0..199
    v16i acc[5] = {};
    const char* ab = xpl + ((size_t)mt * 24) * 4 * 1024 + (size_t)l * 16;

    for (int kcb = 0; kcb < 3; ++kcb) {
        __syncthreads();
        const char* src = wpl + ((size_t)(nt * 24 + kcb * 8)) * 4 * 1024;
#pragma unroll
        for (int i = 0; i < 4; ++i) {
            int off = tid * 16 + i * 8192;
            *(int4*)(wlds + off) = *(const int4*)(src + off);
        }
        __syncthreads();
#pragma unroll
        for (int kc = 0; kc < 8; ++kc) {
            const char* a8 = ab + (size_t)(kcb * 8 + kc) * 4096;
            const char* w8 = wlds + (size_t)kc * 4096 + (size_t)l * 16;
            v4i xv[4], wv[4];
#pragma unroll
            for (int p = 0; p < 4; ++p) {
                xv[p] = *(const v4i*)(a8 + (size_t)p * 1024);
                wv[p] = *(const v4i*)(w8 + (size_t)p * 1024);
            }
            acc[4] = __builtin_amdgcn_mfma_i32_32x32x32_i8(xv[3], wv[3], acc[4], 0,0,0);
            acc[3] = __builtin_amdgcn_mfma_i32_32x32x32_i8(xv[2], wv[3], acc[3], 0,0,0);
            acc[3] = __builtin_amdgcn_mfma_i32_32x32x32_i8(xv[3], wv[2], acc[3], 0,0,0);
            acc[2] = __builtin_amdgcn_mfma_i32_32x32x32_i8(xv[1], wv[3], acc[2], 0,0,0);
            acc[2] = __builtin_amdgcn_mfma_i32_32x32x32_i8(xv[2], wv[2], acc[2], 0,0,0);
            acc[2] = __builtin_amdgcn_mfma_i32_32x32x32_i8(xv[3], wv[1], acc[2], 0,0,0);
            acc[1] = __builtin_amdgcn_mfma_i32_32x32x32_i8(xv[0], wv[3], acc[1], 0,0,0);
            acc[1] = __builtin_amdgcn_mfma_i32_32x32x32_i8(xv[1], wv[2], acc[1], 0,0,0);
            acc[1] = __builtin_amdgcn_mfma_i32_32x32x32_i8(xv[2], wv[1], acc[1], 0,0,0);
            acc[1] = __builtin_amdgcn_mfma_i32_32x32x32_i8(xv[3], wv[0], acc[1], 0,0,0);
            acc[0] = __builtin_amdgcn_mfma_i32_32x32x32_i8(xv[0], wv[2], acc[0], 0,0,0);
            acc[0] = __builtin_amdgcn_mfma_i32_32x32x32_i8(xv[1], wv[1], acc[0], 0,0,0);
            acc[0] = __builtin_amdgcn_mfma_i32_32x32x32_i8(xv[2], wv[0], acc[0], 0,0,0);
        }
    }
    int half = l >> 5, lr = l & 31;
    int col = nt * 32 + lr;
    double bv = (double)bias[col];
#pragma unroll
    for (int e = 0; e < 16; ++e) {
        int row = (e & 3) + 8 * (e >> 2) + 4 * half;
        int r = mt * 32 + row;
        double hv = (((((double)acc[4][e] * 256.0 + (double)acc[3][e]) * 256.0
                      + (double)acc[2][e]) * 256.0 + (double)acc[1][e]) * 256.0 + (double)acc[0][e]);
        double v = hv * 7.105427357601002e-15 + bv;   // 256^2 * 2^-63 = 2^-47
        float cf = (float)v;
        float rf = (float)(v - (double)cf);
        size_t off = (size_t)r * HH + col;
        c_out[off] = cf; res_out[off] = rf;
    }
}

// ---------------- GEMM2/3: c[6400][2048] = spikes(i8) @ W(4pl)^T + b ----------------
// 8 waves/block; each wave 1mt x 2nt (acc[2][4], 128 VGPR). W for the 2 nts
// double-buffered in LDS (2x64 KB) with register prefetch. No VGPR cap.
__global__ __launch_bounds__(512)
void k_gemm23(const char* __restrict__ aq, const char* __restrict__ wpl,
              const float* __restrict__ bias,
              float* __restrict__ c_out, float* __restrict__ res_out)
{
    __shared__ char wlds[2][65536];
    int tid = threadIdx.x;
    int wm = tid >> 6, l = tid & 63;
    int half = l >> 5, lr = l & 31;
    int nt0 = blockIdx.x * 2;          // 0..62 (fast dim -> XCD = blk%8)
    int mt = blockIdx.y * 8 + wm;      // 0..199
    v16i acc[2][4] = {};
    const char* ab = aq + (size_t)mt * 65536 + (size_t)l * 16;
    const char* wsrc = wpl + ((size_t)nt0 * 64) * 4 * 1024;   // 512 KB (2 nts, contiguous)

    int4 st[8];
#pragma unroll
    for (int i = 0; i < 8; ++i) {
        int off = tid * 16 + i * 8192;
        int j = off >> 15, q = off & 32767;
        st[i] = *(const int4*)(wsrc + (size_t)j * 262144 + q);
    }
#pragma unroll
    for (int i = 0; i < 8; ++i)
        *(int4*)(&wlds[0][tid * 16 + i * 8192]) = st[i];

    for (int kcb = 0; kcb < 8; ++kcb) {
        if (kcb < 7) {
#pragma unroll
            for (int i = 0; i < 8; ++i) {
                int off = tid * 16 + i * 8192;
                int j = off >> 15, q = off & 32767;
                st[i] = *(const int4*)(wsrc + (size_t)j * 262144 + (size_t)(kcb + 1) * 32768 + q);
            }
        }
        __syncthreads();
        const char* lb = wlds[kcb & 1];
#pragma unroll
        for (int kc = 0; kc < 8; ++kc) {
            v4i a = *(const v4i*)(ab + (size_t)(kcb * 8 + kc) * 1024);
#pragma unroll
            for (int j = 0; j < 2; ++j) {
                const char* w8 = lb + j * 32768 + kc * 4096 + l * 16;
                v4i w0 = *(const v4i*)(w8);
                v4i w1 = *(const v4i*)(w8 + 1024);
                v4i w2 = *(const v4i*)(w8 + 2048);
                v4i w3 = *(const v4i*)(w8 + 3072);
                acc[j][0] = __builtin_amdgcn_mfma_i32_32x32x32_i8(a, w0, acc[j][0], 0,0,0);
                acc[j][1] = __builtin_amdgcn_mfma_i32_32x32x32_i8(a, w1, acc[j][1], 0,0,0);
                acc[j][2] = __builtin_amdgcn_mfma_i32_32x32x32_i8(a, w2, acc[j][2], 0,0,0);
                acc[j][3] = __builtin_amdgcn_mfma_i32_32x32x32_i8(a, w3, acc[j][3], 0,0,0);
            }
        }
        if (kcb < 7) {
#pragma unroll
            for (int i = 0; i < 8; ++i)
                *(int4*)(&wlds[(kcb + 1) & 1][tid * 16 + i * 8192]) = st[i];
        }
    }

#pragma unroll
    for (int j = 0; j < 2; ++j) {
        int col = (nt0 + j) * 32 + lr;
        double bv = (double)bias[col];
#pragma unroll
        for (int e = 0; e < 16; ++e) {
            int row = (e & 3) + 8 * (e >> 2) + 4 * half;
            size_t off = (size_t)(mt * 32 + row) * HH + col;
            double dot = ((((double)acc[j][3][e] * 256.0 + (double)acc[j][2][e]) * 256.0
                          + (double)acc[j][1][e]) * 256.0 + (double)acc[j][0][e]) * 2.9103830456733704e-11; // 2^-35
            double v = dot + bv;
            float cf = (float)v;
            float rf = (float)(v - (double)cf);
            c_out[off] = cf; res_out[off] = rf;
        }
    }
}

// ---------------- LIF scan: 1 element/thread, 25-step fp64 recursion ----------------
template<bool SWZ>
__global__ __launch_bounds__(256)
void k_scan(const float* __restrict__ c, float* __restrict__ res_m,
            float* __restrict__ s, char* __restrict__ sq,
            const float* __restrict__ beta_p, const float* __restrict__ thr_p)
{
    int idx = blockIdx.x * 256 + threadIdx.x;   // 524288 = PT
    int b = idx >> 11, n = idx & 2047;
    double beta = fmin(fmax((double)*beta_p, 0.0), 1.0);
    double thr  = (double)*thr_p;
    double mem = 0.0;
    for (int t = 0; t < T_; ++t) {
        size_t off = (size_t)t * PT + idx;
        double cur = (double)c[off] + (double)res_m[off];
        double reset = (mem > thr) ? 1.0 : 0.0;
        mem = beta * mem + cur - reset * thr;
        bool sp = mem > thr;
        res_m[off] = (float)mem;
        s[off] = sp ? 1.f : 0.f;
        if (SWZ) {
            int r = t * 256 + b;
            size_t sa = ((size_t)((r >> 5) * 64 + (n >> 5))) * 1024
                      + (size_t)((((n >> 4) & 1) * 32 + (r & 31))) * 16 + (n & 15);
            sq[sa] = sp ? 1 : 0;
        }
    }
}

// ---------------- GEMM4 (exact i8): c4[6400][10] = spikes @ W4(4pl)^T + b4 ----------------
__global__ __launch_bounds__(64)
void k_gemm4i8(const char* __restrict__ aq, const char* __restrict__ wpl,
               const float* __restrict__ bias,
               float* __restrict__ c_out, float* __restrict__ res_out)
{
    int l = threadIdx.x;
    int half = l >> 5, lr = l & 31;
    int mt = blockIdx.x;               // 0..199
    v16i acc[4] = {};
    const char* ab = aq + (size_t)mt * 65536 + (size_t)l * 16;
    const char* wb = wpl + (size_t)l * 16;
#pragma unroll 4
    for (int kc = 0; kc < 64; ++kc) {
        v4i a = *(const v4i*)(ab + (size_t)kc * 1024);
        const char* w8 = wb + (size_t)kc * 4096;
        v4i w0 = *(const v4i*)(w8);
        v4i w1 = *(const v4i*)(w8 + 1024);
        v4i w2 = *(const v4i*)(w8 + 2048);
        v4i w3 = *(const v4i*)(w8 + 3072);
        acc[0] = __builtin_amdgcn_mfma_i32_32x32x32_i8(a, w0, acc[0], 0,0,0);
        acc[1] = __builtin_amdgcn_mfma_i32_32x32x32_i8(a, w1, acc[1], 0,0,0);
        acc[2] = __builtin_amdgcn_mfma_i32_32x32x32_i8(a, w2, acc[2], 0,0,0);
        acc[3] = __builtin_amdgcn_mfma_i32_32x32x32_i8(a, w3, acc[3], 0,0,0);
    }
    if (lr < 10) {
        double bv = (double)bias[lr];
#pragma unroll
        for (int e = 0; e < 16; ++e) {
            int row = (e & 3) + 8 * (e >> 2) + 4 * half;
            size_t off = (size_t)(mt * 32 + row) * 10 + lr;
            double dot = ((((double)acc[3][e] * 256.0 + (double)acc[2][e]) * 256.0
                          + (double)acc[1][e]) * 256.0 + (double)acc[0][e]) * 2.9103830456733704e-11;
            double v = dot + bv;
            float cf = (float)v;
            float rf = (float)(v - (double)cf);
            c_out[off] = cf; res_out[off] = rf;
        }
    }
}

__global__ __launch_bounds__(256)
void k_scan4(const float* __restrict__ c, float* __restrict__ res_m,
             float* __restrict__ s,
             const float* __restrict__ beta_p, const float* __restrict__ thr_p)
{
    int idx = blockIdx.x * 256 + threadIdx.x;
    if (idx >= PT4) return;
    double beta = fmin(fmax((double)*beta_p, 0.0), 1.0);
    double thr  = (double)*thr_p;
    double mem = 0.0;
    for (int t = 0; t < T_; ++t) {
        size_t off = (size_t)t * PT4 + idx;
        double cur = (double)c[off] + (double)res_m[off];
        double reset = (mem > thr) ? 1.0 : 0.0;
        mem = beta * mem + cur - reset * thr;
        res_m[off] = (float)mem;
        s[off] = (mem > thr) ? 1.f : 0.f;
    }
}

// ---------------- fp64 fallback (round-2 verified) ----------------
#define BM 32
#define BN 64
#define BK 32
__global__ __launch_bounds__(256)
void gemm_lif_f64(const float* __restrict__ A, int lda, const float* __restrict__ W,
                  const float* __restrict__ bias, const double* __restrict__ m64_in,
                  const float* __restrict__ m32_in, double* __restrict__ m64_out,
                  float* __restrict__ cur_out, float* __restrict__ mem_out, float* __restrict__ spk_out,
                  const float* __restrict__ beta_p, const float* __restrict__ thr_p, int K, int N)
{
    __shared__ double As[BK][BM + 4];
    __shared__ double Ws[BK][BN + 4];
    const int tid = threadIdx.x;
    const int bm = blockIdx.y * BM, bn = blockIdx.x * BN;
    const int tx = tid & 15, ty = tid >> 4;
    const int n0 = tx * 4, m0 = ty * 2;
    const int arow = tid >> 3, acol = (tid & 7) * 4;
    double acc[2][4] = {{0,0,0,0},{0,0,0,0}};
    for (int kt = 0; kt < K; kt += BK) {
        float4 av = *reinterpret_cast<const float4*>(A + (size_t)(bm + arow) * lda + kt + acol);
        As[acol+0][arow]=av.x; As[acol+1][arow]=av.y; As[acol+2][arow]=av.z; As[acol+3][arow]=av.w;
#pragma unroll
        for (int r = 0; r < 2; ++r) {
            int n = arow + r * 32;
            float4 wv = *reinterpret_cast<const float4*>(W + (size_t)(bn + n) * K + kt + acol);
            Ws[acol+0][n]=wv.x; Ws[acol+1][n]=wv.y; Ws[acol+2][n]=wv.z; Ws[acol+3][n]=wv.w;
        }
        __syncthreads();
#pragma unroll
        for (int k = 0; k < BK; ++k) {
            double2 a  = *reinterpret_cast<const double2*>(&As[k][m0]);
            double2 w0 = *reinterpret_cast<const double2*>(&Ws[k][n0]);
            double2 w1 = *reinterpret_cast<const double2*>(&Ws[k][n0 + 2]);
            acc[0][0]+=a.x*w0.x; acc[0][1]+=a.x*w0.y; acc[0][2]+=a.x*w1.x; acc[0][3]+=a.x*w1.y;
            acc[1][0]+=a.y*w0.x; acc[1][1]+=a.y*w0.y; acc[1][2]+=a.y*w1.x; acc[1][3]+=a.y*w1.y;
        }
        __syncthreads();
    }
    const double beta = fmin(fmax((double)*beta_p, 0.0), 1.0);
    const double thr  = (double)*thr_p;
#pragma unroll
    for (int r = 0; r < 2; ++r) {
        const size_t off = (size_t)(bm + m0 + r) * N + bn + n0;
        float4 cf, mf, sf;
        float* cfp=&cf.x; float* mfp=&mf.x; float* sfp=&sf.x;
#pragma unroll
        for (int j = 0; j < 4; ++j) {
            double cur = acc[r][j] + (double)bias[bn + n0 + j];
            double mp = m64_in ? m64_in[off + j] : (m32_in ? (double)m32_in[off + j] : 0.0);
            double reset = (mp > thr) ? 1.0 : 0.0;
            double mem = beta * mp + cur - reset * thr;
            cfp[j]=(float)cur; mfp[j]=(float)mem; sfp[j]=(mem > thr)?1.f:0.f;
            if (m64_out) m64_out[off + j] = mem;
        }
        *reinterpret_cast<float4*>(cur_out + off) = cf;
        *reinterpret_cast<float4*>(mem_out + off) = mf;
        *reinterpret_cast<float4*>(spk_out + off) = sf;
    }
}

__global__ __launch_bounds__(256)
void k_fc4_lif(const float* __restrict__ A, const float* __restrict__ W,
               const float* __restrict__ bias, double* __restrict__ m4ws,
               float* __restrict__ c4, float* __restrict__ m4, float* __restrict__ s4,
               const float* __restrict__ beta_p, const float* __restrict__ thr_p, int t0)
{
    int wid = threadIdx.x >> 6, lane = threadIdx.x & 63;
    int i = blockIdx.x * 4 + wid;
    double a[32];
#pragma unroll
    for (int m = 0; m < 32; ++m)
        a[m] = (double)A[(size_t)i * HH + lane + 64 * m];
    double beta = fmin(fmax((double)*beta_p, 0.0), 1.0);
    double thr  = (double)*thr_p;
    for (int j = 0; j < 10; ++j) {
        double s = 0.0;
#pragma unroll
        for (int m = 0; m < 32; ++m)
            s += a[m] * (double)W[(size_t)j * HH + lane + 64 * m];
#pragma unroll
        for (int o = 32; o > 0; o >>= 1)
            s += __shfl_down(s, o);
        if (lane == 0) {
            double cur = s + (double)bias[j];
            double mp = t0 ? 0.0 : m4ws[i * 10 + j];
            double reset = (mp > thr) ? 1.0 : 0.0;
            double mem = beta * mp + cur - reset * thr;
            c4[i * 10 + j] = (float)cur; m4[i * 10 + j] = (float)mem;
            s4[i * 10 + j] = (mem > thr) ? 1.f : 0.f;
            m4ws[i * 10 + j] = mem;
        }
    }
}

extern "C" void kernel_launch(void* const* d_in, const int* in_sizes, int n_in,
                              void* d_out, int out_size, void* d_ws, size_t ws_size,
                              hipStream_t stream) {
    const float* x  = (const float*)d_in[0];
    const float* W1 = (const float*)d_in[1];  const float* b1 = (const float*)d_in[2];
    const float* W2 = (const float*)d_in[3];  const float* b2 = (const float*)d_in[4];
    const float* W3 = (const float*)d_in[5];  const float* b3 = (const float*)d_in[6];
    const float* W4 = (const float*)d_in[7];  const float* b4 = (const float*)d_in[8];
    const float* beta1 = (const float*)d_in[9];  const float* beta2 = (const float*)d_in[10];
    const float* beta3 = (const float*)d_in[11]; const float* beta4 = (const float*)d_in[12];
    const float* thr1 = (const float*)d_in[13];  const float* thr2 = (const float*)d_in[14];
    const float* thr3 = (const float*)d_in[15];  const float* thr4 = (const float*)d_in[16];

    float* out = (float*)d_out;
    const size_t SB = (size_t)T_ * PT, SB4 = (size_t)T_ * PT4;
    float* s1 = out;            float* s2 = out + SB;   float* s3 = out + 2*SB; float* s4 = out + 3*SB;
    float* m1 = s4 + SB4;       float* m2 = m1 + SB;    float* m3 = m1 + 2*SB;  float* m4 = m1 + 3*SB;
    float* c1 = m4 + SB4;       float* c2 = c1 + SB;    float* c3 = c1 + 2*SB;  float* c4 = c1 + 3*SB;

    const size_t XPL = 4ull*6400*768;        // 19.7 MB
    const size_t W1PL = 4ull*2048*768;       // 6.3 MB
    const size_t W23PL = 4ull*2048*2048;     // 16.8 MB each
    const size_t W4PL = 64ull*4*1024;        // 0.26 MB (1 ntile)
    const size_t SQ = 6400ull*2048;          // 13.1 MB each
    size_t need = XPL + W1PL + 2*W23PL + 2*SQ + W4PL;   // ~86 MB

    if (ws_size >= need) {
        char* w = (char*)d_ws;
        char* xpl  = w;              char* w1pl = xpl + XPL;
        char* w2pl = w1pl + W1PL;    char* w3pl = w2pl + W23PL;
        char* s1q  = w3pl + W23PL;   char* s2q  = s1q + SQ;
        char* w4pl = s2q + SQ;
        // s3q aliases s1q (dead after gemm2 reads it; scan3 fully rewrites it)
        char* s3q  = s1q;

        k_decomp_all<<<3637, 256, 0, stream>>>(x, xpl, W1, w1pl, W2, w2pl, W3, w3pl, W4, w4pl);

        k_gemm1<<<dim3(64, 25), 512, 0, stream>>>(xpl, w1pl, b1, c1, m1);
        k_scan<true><<<2048, 256, 0, stream>>>(c1, m1, s1, s1q, beta1, thr1);
        k_gemm23<<<dim3(32, 25), 512, 0, stream>>>(s1q, w2pl, b2, c2, m2);
        k_scan<true><<<2048, 256, 0, stream>>>(c2, m2, s2, s2q, beta2, thr2);
        k_gemm23<<<dim3(32, 25), 512, 0, stream>>>(s2q, w3pl, b3, c3, m3);
        k_scan<true><<<2048, 256, 0, stream>>>(c3, m3, s3, s3q, beta3, thr3);
        k_gemm4i8<<<200, 64, 0, stream>>>(s3q, w4pl, b4, c4, m4);
        k_scan4<<<10, 256, 0, stream>>>(c4, m4, s4, beta4, thr4);
        return;
    }

    // -------- fp64 fallback (round-2 verified) --------
    const size_t NL = PT;
    const size_t WS_NEED = (3 * NL + PT4) * sizeof(double);
    const bool use64 = (d_ws != nullptr) && (ws_size >= WS_NEED);
    double* wsd = (double*)d_ws;
    double* mm1 = use64 ? wsd : nullptr;
    double* mm2 = use64 ? wsd + NL : nullptr;
    double* mm3 = use64 ? wsd + 2 * NL : nullptr;
    double* mm4 = use64 ? wsd + 3 * NL : nullptr;
    const dim3 grid(HH / BN, BB / BM);
    for (int t = 0; t < T_; ++t) {
        size_t po = (size_t)t * PT, po4 = (size_t)t * PT4;
        gemm_lif_f64<<<grid, 256, 0, stream>>>(x + (size_t)t * DIN, T_ * DIN, W1, b1,
            t ? mm1 : nullptr, t ? m1 + po - PT : nullptr, mm1,
            c1 + po, m1 + po, s1 + po, beta1, thr1, DIN, HH);
        gemm_lif_f64<<<grid, 256, 0, stream>>>(s1 + po, HH, W2, b2,
            t ? mm2 : nullptr, t ? m2 + po - PT : nullptr, mm2,
            c2 + po, m2 + po, s2 + po, beta2, thr2, HH, HH);
        gemm_lif_f64<<<grid, 256, 0, stream>>>(s2 + po, HH, W3, b3,
            t ? mm3 : nullptr, t ? m3 + po - PT : nullptr, mm3,
            c3 + po, m3 + po, s3 + po, beta3, thr3, HH, HH);
        k_fc4_lif<<<64, 256, 0, stream>>>(s3 + po, W4, b4,
            mm4 ? mm4 : (double*)d_ws, c4 + po4, m4 + po4, s4 + po4, beta4, thr4, t == 0);
    }
}

// Round 12
// 577.861 us; speedup vs baseline: 1.3769x; 1.3769x over previous
//
#include <hip/hip_runtime.h>

// SNN 4-layer LIF, T=25, B=256 — batched-time formulation (r8 configuration,
// the measured optimum: 588 us). GEMMs for all 25 t at once (M=6400): i8
// digit planes, i32 MFMA accum (exact), fp64 reconstruct. Sequential part =
// elementwise membrane scans (1 elem/thread). GEMM blocks: 8 waves (8 mt x
// 1 nt), W-chunk staged in LDS (32 KB single-buffer, 2 barriers/chunk).
// r9 (dbuf + launch_bounds cap -> spills) and r11 (2-nt/128KB LDS -> 1
// block/CU) both regressed; this form is the best measured.
// nt is the fast blockIdx dim (XCD = nt%8 pins each W-slice in one L2).
// cur crosses kernels as f32 + f32 residual (res lives in the m-region of
// d_out until the scan overwrites it with m).

typedef int v4i  __attribute__((ext_vector_type(4)));
typedef int v16i __attribute__((ext_vector_type(16)));

#define T_   25
#define BB   256
#define DIN  768
#define HH   2048
#define PT   (BB*HH)
#define PT4  (BB*10)

// ---------------- digit decomposition (verified r5-r11) ----------------
// x[B][T][DIN] -> 4 planes @2^28, A-swizzled [rtile(200)][kc(24)][pl(4)][lane][16]
__global__ __launch_bounds__(256)
void k_decomp_x(const float* __restrict__ x, char* __restrict__ xpl)
{
    int gid = blockIdx.x * 256 + threadIdx.x;      // 6400*48
    int r = gid / 48, rem = gid % 48;
    int kc = rem >> 1, h = rem & 1;
    int t = r >> 8, b = r & 255;
    const float* src = x + ((size_t)b * T_ + t) * DIN + kc * 32 + h * 16;
    alignas(16) char dig[4][16];
#pragma unroll
    for (int e = 0; e < 16; ++e) {
        long long V = llround((double)src[e] * 268435456.0);  // 2^28
#pragma unroll
        for (int p = 0; p < 3; ++p) {
            int d = (int)(V & 255); if (d >= 128) d -= 256;
            dig[p][e] = (char)d; V = (V - d) >> 8;
        }
        dig[3][e] = (char)V;
    }
    size_t base = (((size_t)(r >> 5) * 24 + kc) * 4) * 1024 + (size_t)(h * 32 + (r & 31)) * 16;
#pragma unroll
    for (int p = 0; p < 4; ++p)
        *(int4*)(xpl + base + (size_t)p * 1024) = *(const int4*)dig[p];
}

// W[NROWS][K] -> NDIG planes @2^QSH, B-swizzled [ntile][kc(KC)][pl][lane][16]
template<int NDIG, int QSH, int KC>
__global__ __launch_bounds__(256)
void k_decomp_w(const float* __restrict__ W, char* __restrict__ wpl, int K, int NROWS)
{
    int gid = blockIdx.x * 256 + threadIdx.x;
    int n = gid / (KC * 2), rem = gid % (KC * 2);
    if (n >= NROWS) return;
    int kc = rem >> 1, h = rem & 1;
    const float* src = W + (size_t)n * K + kc * 32 + h * 16;
    const double scale = (double)(1ULL << QSH);
    alignas(16) char dig[NDIG][16];
#pragma unroll
    for (int e = 0; e < 16; ++e) {
        long long V = llround((double)src[e] * scale);
#pragma unroll
        for (int p = 0; p < NDIG - 1; ++p) {
            int d = (int)(V & 255); if (d >= 128) d -= 256;
            dig[p][e] = (char)d; V = (V - d) >> 8;
        }
        dig[NDIG - 1][e] = (char)V;
    }
    size_t base = (((size_t)(n >> 5) * KC + kc) * NDIG) * 1024 + (size_t)(h * 32 + (n & 31)) * 16;
#pragma unroll
    for (int p = 0; p < NDIG; ++p)
        *(int4*)(wpl + base + (size_t)p * 1024) = *(const int4*)dig[p];
}

// ---------------- GEMM1: c1[6400][2048] = x(4pl) @ W1(4pl)^T + b1 ----------------
// 13 digit pairs s>=2 (verified r5-r11). 8 waves/block, W chunk in LDS.
__global__ __launch_bounds__(512)
void k_gemm1(const char* __restrict__ xpl, const char* __restrict__ wpl,
             const float* __restrict__ bias, float* __restrict__ c_out,
             float* __restrict__ res_out)
{
    __shared__ char wlds[32768];
    int tid = threadIdx.x;
    int wm = tid >> 6, l = tid & 63;
    int nt = blockIdx.x;               // 0..63 (fast dim -> XCD = nt%8)
    int mt = blockIdx.y * 8 + wm;      // 0..199
    v16i acc[5] = {};
    const char* ab = xpl + ((size_t)mt * 24) * 4 * 1024 + (size_t)l * 16;

    for (int kcb = 0; kcb < 3; ++kcb) {
        __syncthreads();
        const char* src = wpl + ((size_t)(nt * 24 + kcb * 8)) * 4 * 1024;
#pragma unroll
        for (int i = 0; i < 4; ++i) {
            int off = tid * 16 + i * 8192;
            *(int4*)(wlds + off) = *(const int4*)(src + off);
        }
        __syncthreads();
#pragma unroll
        for (int kc = 0; kc < 8; ++kc) {
            const char* a8 = ab + (size_t)(kcb * 8 + kc) * 4096;
            const char* w8 = wlds + (size_t)kc * 4096 + (size_t)l * 16;
            v4i xv[4], wv[4];
#pragma unroll
            for (int p = 0; p < 4; ++p) {
                xv[p] = *(const v4i*)(a8 + (size_t)p * 1024);
                wv[p] = *(const v4i*)(w8 + (size_t)p * 1024);
            }
            acc[4] = __builtin_amdgcn_mfma_i32_32x32x32_i8(xv[3], wv[3], acc[4], 0,0,0);
            acc[3] = __builtin_amdgcn_mfma_i32_32x32x32_i8(xv[2], wv[3], acc[3], 0,0,0);
            acc[3] = __builtin_amdgcn_mfma_i32_32x32x32_i8(xv[3], wv[2], acc[3], 0,0,0);
            acc[2] = __builtin_amdgcn_mfma_i32_32x32x32_i8(xv[1], wv[3], acc[2], 0,0,0);
            acc[2] = __builtin_amdgcn_mfma_i32_32x32x32_i8(xv[2], wv[2], acc[2], 0,0,0);
            acc[2] = __builtin_amdgcn_mfma_i32_32x32x32_i8(xv[3], wv[1], acc[2], 0,0,0);
            acc[1] = __builtin_amdgcn_mfma_i32_32x32x32_i8(xv[0], wv[3], acc[1], 0,0,0);
            acc[1] = __builtin_amdgcn_mfma_i32_32x32x32_i8(xv[1], wv[2], acc[1], 0,0,0);
            acc[1] = __builtin_amdgcn_mfma_i32_32x32x32_i8(xv[2], wv[1], acc[1], 0,0,0);
            acc[1] = __builtin_amdgcn_mfma_i32_32x32x32_i8(xv[3], wv[0], acc[1], 0,0,0);
            acc[0] = __builtin_amdgcn_mfma_i32_32x32x32_i8(xv[0], wv[2], acc[0], 0,0,0);
            acc[0] = __builtin_amdgcn_mfma_i32_32x32x32_i8(xv[1], wv[1], acc[0], 0,0,0);
            acc[0] = __builtin_amdgcn_mfma_i32_32x32x32_i8(xv[2], wv[0], acc[0], 0,0,0);
        }
    }
    int half = l >> 5, lr = l & 31;
    int col = nt * 32 + lr;
    double bv = (double)bias[col];
#pragma unroll
    for (int e = 0; e < 16; ++e) {
        int row = (e & 3) + 8 * (e >> 2) + 4 * half;
        int r = mt * 32 + row;
        double hv = (((((double)acc[4][e] * 256.0 + (double)acc[3][e]) * 256.0
                      + (double)acc[2][e]) * 256.0 + (double)acc[1][e]) * 256.0 + (double)acc[0][e]);
        double v = hv * 7.105427357601002e-15 + bv;   // 256^2 * 2^-63 = 2^-47
        float cf = (float)v;
        float rf = (float)(v - (double)cf);
        size_t off = (size_t)r * HH + col;
        c_out[off] = cf; res_out[off] = rf;
    }
}

// ---------------- GEMM2/3: c[6400][2048] = spikes(i8) @ W(4pl)^T + b ----------------
// 8 waves/block (8 mt x 1 nt), W chunk staged in LDS, 8 chunks (r8-measured form).
__global__ __launch_bounds__(512)
void k_gemm23(const char* __restrict__ aq, const char* __restrict__ wpl,
              const float* __restrict__ bias,
              float* __restrict__ c_out, float* __restrict__ res_out)
{
    __shared__ char wlds[32768];
    int tid = threadIdx.x;
    int wm = tid >> 6, l = tid & 63;
    int half = l >> 5, lr = l & 31;
    int nt = blockIdx.x;               // 0..63 (fast dim)
    int mt = blockIdx.y * 8 + wm;      // 0..199
    v16i acc[4] = {};
    const char* ab = aq + (size_t)mt * 65536 + (size_t)l * 16;

    for (int kcb = 0; kcb < 8; ++kcb) {
        __syncthreads();
        const char* src = wpl + ((size_t)(nt * 64 + kcb * 8)) * 4 * 1024;
#pragma unroll
        for (int i = 0; i < 4; ++i) {
            int off = tid * 16 + i * 8192;
            *(int4*)(wlds + off) = *(const int4*)(src + off);
        }
        __syncthreads();
#pragma unroll
        for (int kc = 0; kc < 8; ++kc) {
            v4i a  = *(const v4i*)(ab + (size_t)(kcb * 8 + kc) * 1024);
            const char* w8 = wlds + (size_t)kc * 4096 + (size_t)l * 16;
            v4i w0 = *(const v4i*)(w8);
            v4i w1 = *(const v4i*)(w8 + 1024);
            v4i w2 = *(const v4i*)(w8 + 2048);
            v4i w3 = *(const v4i*)(w8 + 3072);
            acc[0] = __builtin_amdgcn_mfma_i32_32x32x32_i8(a, w0, acc[0], 0,0,0);
            acc[1] = __builtin_amdgcn_mfma_i32_32x32x32_i8(a, w1, acc[1], 0,0,0);
            acc[2] = __builtin_amdgcn_mfma_i32_32x32x32_i8(a, w2, acc[2], 0,0,0);
            acc[3] = __builtin_amdgcn_mfma_i32_32x32x32_i8(a, w3, acc[3], 0,0,0);
        }
    }
    int col = nt * 32 + lr;
    double bv = (double)bias[col];
#pragma unroll
    for (int e = 0; e < 16; ++e) {
        int row = (e & 3) + 8 * (e >> 2) + 4 * half;
        size_t off = (size_t)(mt * 32 + row) * HH + col;
        double dot = ((((double)acc[3][e] * 256.0 + (double)acc[2][e]) * 256.0
                      + (double)acc[1][e]) * 256.0 + (double)acc[0][e]) * 2.9103830456733704e-11; // 2^-35
        double v = dot + bv;
        float cf = (float)v;
        float rf = (float)(v - (double)cf);
        c_out[off] = cf; res_out[off] = rf;
    }
}

// ---------------- LIF scan: 1 element/thread, 25-step fp64 recursion ----------------
template<bool SWZ>
__global__ __launch_bounds__(256)
void k_scan(const float* __restrict__ c, float* __restrict__ res_m,
            float* __restrict__ s, char* __restrict__ sq,
            const float* __restrict__ beta_p, const float* __restrict__ thr_p)
{
    int idx = blockIdx.x * 256 + threadIdx.x;   // 524288 = PT
    int b = idx >> 11, n = idx & 2047;
    double beta = fmin(fmax((double)*beta_p, 0.0), 1.0);
    double thr  = (double)*thr_p;
    double mem = 0.0;
    for (int t = 0; t < T_; ++t) {
        size_t off = (size_t)t * PT + idx;
        double cur = (double)c[off] + (double)res_m[off];
        double reset = (mem > thr) ? 1.0 : 0.0;
        mem = beta * mem + cur - reset * thr;
        bool sp = mem > thr;
        res_m[off] = (float)mem;
        s[off] = sp ? 1.f : 0.f;
        if (SWZ) {
            int r = t * 256 + b;
            size_t sa = ((size_t)((r >> 5) * 64 + (n >> 5))) * 1024
                      + (size_t)((((n >> 4) & 1) * 32 + (r & 31))) * 16 + (n & 15);
            sq[sa] = sp ? 1 : 0;
        }
    }
}

// ---------------- GEMM4: c4[6400][10] = s3 @ W4^T + b4 (fp64 wave-dot) ----------------
__global__ __launch_bounds__(256)
void k_gemm4(const float* __restrict__ A, const float* __restrict__ W,
             const float* __restrict__ bias,
             float* __restrict__ c_out, float* __restrict__ res_out)
{
    int wid = threadIdx.x >> 6, lane = threadIdx.x & 63;
    int i = blockIdx.x * 4 + wid;     // 0..6399
    double a[32];
#pragma unroll
    for (int m = 0; m < 32; ++m)
        a[m] = (double)A[(size_t)i * HH + lane + 64 * m];
    for (int j = 0; j < 10; ++j) {
        double s = 0.0;
#pragma unroll
        for (int m = 0; m < 32; ++m)
            s += a[m] * (double)W[(size_t)j * HH + lane + 64 * m];
#pragma unroll
        for (int o = 32; o > 0; o >>= 1)
            s += __shfl_down(s, o);
        if (lane == 0) {
            double v = s + (double)bias[j];
            float cf = (float)v;
            float rf = (float)(v - (double)cf);
            c_out[i * 10 + j] = cf; res_out[i * 10 + j] = rf;
        }
    }
}

__global__ __launch_bounds__(256)
void k_scan4(const float* __restrict__ c, float* __restrict__ res_m,
             float* __restrict__ s,
             const float* __restrict__ beta_p, const float* __restrict__ thr_p)
{
    int idx = blockIdx.x * 256 + threadIdx.x;
    if (idx >= PT4) return;
    double beta = fmin(fmax((double)*beta_p, 0.0), 1.0);
    double thr  = (double)*thr_p;
    double mem = 0.0;
    for (int t = 0; t < T_; ++t) {
        size_t off = (size_t)t * PT4 + idx;
        double cur = (double)c[off] + (double)res_m[off];
        double reset = (mem > thr) ? 1.0 : 0.0;
        mem = beta * mem + cur - reset * thr;
        res_m[off] = (float)mem;
        s[off] = (mem > thr) ? 1.f : 0.f;
    }
}

// ---------------- fp64 fallback (round-2 verified) ----------------
#define BM 32
#define BN 64
#define BK 32
__global__ __launch_bounds__(256)
void gemm_lif_f64(const float* __restrict__ A, int lda, const float* __restrict__ W,
                  const float* __restrict__ bias, const double* __restrict__ m64_in,
                  const float* __restrict__ m32_in, double* __restrict__ m64_out,
                  float* __restrict__ cur_out, float* __restrict__ mem_out, float* __restrict__ spk_out,
                  const float* __restrict__ beta_p, const float* __restrict__ thr_p, int K, int N)
{
    __shared__ double As[BK][BM + 4];
    __shared__ double Ws[BK][BN + 4];
    const int tid = threadIdx.x;
    const int bm = blockIdx.y * BM, bn = blockIdx.x * BN;
    const int tx = tid & 15, ty = tid >> 4;
    const int n0 = tx * 4, m0 = ty * 2;
    const int arow = tid >> 3, acol = (tid & 7) * 4;
    double acc[2][4] = {{0,0,0,0},{0,0,0,0}};
    for (int kt = 0; kt < K; kt += BK) {
        float4 av = *reinterpret_cast<const float4*>(A + (size_t)(bm + arow) * lda + kt + acol);
        As[acol+0][arow]=av.x; As[acol+1][arow]=av.y; As[acol+2][arow]=av.z; As[acol+3][arow]=av.w;
#pragma unroll
        for (int r = 0; r < 2; ++r) {
            int n = arow + r * 32;
            float4 wv = *reinterpret_cast<const float4*>(W + (size_t)(bn + n) * K + kt + acol);
            Ws[acol+0][n]=wv.x; Ws[acol+1][n]=wv.y; Ws[acol+2][n]=wv.z; Ws[acol+3][n]=wv.w;
        }
        __syncthreads();
#pragma unroll
        for (int k = 0; k < BK; ++k) {
            double2 a  = *reinterpret_cast<const double2*>(&As[k][m0]);
            double2 w0 = *reinterpret_cast<const double2*>(&Ws[k][n0]);
            double2 w1 = *reinterpret_cast<const double2*>(&Ws[k][n0 + 2]);
            acc[0][0]+=a.x*w0.x; acc[0][1]+=a.x*w0.y; acc[0][2]+=a.x*w1.x; acc[0][3]+=a.x*w1.y;
            acc[1][0]+=a.y*w0.x; acc[1][1]+=a.y*w0.y; acc[1][2]+=a.y*w1.x; acc[1][3]+=a.y*w1.y;
        }
        __syncthreads();
    }
    const double beta = fmin(fmax((double)*beta_p, 0.0), 1.0);
    const double thr  = (double)*thr_p;
#pragma unroll
    for (int r = 0; r < 2; ++r) {
        const size_t off = (size_t)(bm + m0 + r) * N + bn + n0;
        float4 cf, mf, sf;
        float* cfp=&cf.x; float* mfp=&mf.x; float* sfp=&sf.x;
#pragma unroll
        for (int j = 0; j < 4; ++j) {
            double cur = acc[r][j] + (double)bias[bn + n0 + j];
            double mp = m64_in ? m64_in[off + j] : (m32_in ? (double)m32_in[off + j] : 0.0);
            double reset = (mp > thr) ? 1.0 : 0.0;
            double mem = beta * mp + cur - reset * thr;
            cfp[j]=(float)cur; mfp[j]=(float)mem; sfp[j]=(mem > thr)?1.f:0.f;
            if (m64_out) m64_out[off + j] = mem;
        }
        *reinterpret_cast<float4*>(cur_out + off) = cf;
        *reinterpret_cast<float4*>(mem_out + off) = mf;
        *reinterpret_cast<float4*>(spk_out + off) = sf;
    }
}

__global__ __launch_bounds__(256)
void k_fc4_lif(const float* __restrict__ A, const float* __restrict__ W,
               const float* __restrict__ bias, double* __restrict__ m4ws,
               float* __restrict__ c4, float* __restrict__ m4, float* __restrict__ s4,
               const float* __restrict__ beta_p, const float* __restrict__ thr_p, int t0)
{
    int wid = threadIdx.x >> 6, lane = threadIdx.x & 63;
    int i = blockIdx.x * 4 + wid;
    double a[32];
#pragma unroll
    for (int m = 0; m < 32; ++m)
        a[m] = (double)A[(size_t)i * HH + lane + 64 * m];
    double beta = fmin(fmax((double)*beta_p, 0.0), 1.0);
    double thr  = (double)*thr_p;
    for (int j = 0; j < 10; ++j) {
        double s = 0.0;
#pragma unroll
        for (int m = 0; m < 32; ++m)
            s += a[m] * (double)W[(size_t)j * HH + lane + 64 * m];
#pragma unroll
        for (int o = 32; o > 0; o >>= 1)
            s += __shfl_down(s, o);
        if (lane == 0) {
            double cur = s + (double)bias[j];
            double mp = t0 ? 0.0 : m4ws[i * 10 + j];
            double reset = (mp > thr) ? 1.0 : 0.0;
            double mem = beta * mp + cur - reset * thr;
            c4[i * 10 + j] = (float)cur; m4[i * 10 + j] = (float)mem;
            s4[i * 10 + j] = (mem > thr) ? 1.f : 0.f;
            m4ws[i * 10 + j] = mem;
        }
    }
}

extern "C" void kernel_launch(void* const* d_in, const int* in_sizes, int n_in,
                              void* d_out, int out_size, void* d_ws, size_t ws_size,
                              hipStream_t stream) {
    const float* x  = (const float*)d_in[0];
    const float* W1 = (const float*)d_in[1];  const float* b1 = (const float*)d_in[2];
    const float* W2 = (const float*)d_in[3];  const float* b2 = (const float*)d_in[4];
    const float* W3 = (const float*)d_in[5];  const float* b3 = (const float*)d_in[6];
    const float* W4 = (const float*)d_in[7];  const float* b4 = (const float*)d_in[8];
    const float* beta1 = (const float*)d_in[9];  const float* beta2 = (const float*)d_in[10];
    const float* beta3 = (const float*)d_in[11]; const float* beta4 = (const float*)d_in[12];
    const float* thr1 = (const float*)d_in[13];  const float* thr2 = (const float*)d_in[14];
    const float* thr3 = (const float*)d_in[15];  const float* thr4 = (const float*)d_in[16];

    float* out = (float*)d_out;
    const size_t SB = (size_t)T_ * PT, SB4 = (size_t)T_ * PT4;
    float* s1 = out;            float* s2 = out + SB;   float* s3 = out + 2*SB; float* s4 = out + 3*SB;
    float* m1 = s4 + SB4;       float* m2 = m1 + SB;    float* m3 = m1 + 2*SB;  float* m4 = m1 + 3*SB;
    float* c1 = m4 + SB4;       float* c2 = c1 + SB;    float* c3 = c1 + 2*SB;  float* c4 = c1 + 3*SB;

    const size_t XPL = 4ull*6400*768;        // 19.7 MB
    const size_t W1PL = 4ull*2048*768;       // 6.3 MB
    const size_t W23PL = 4ull*2048*2048;     // 16.8 MB each
    const size_t SQ = 6400ull*2048;          // 13.1 MB each
    size_t need = XPL + W1PL + 2*W23PL + 2*SQ;   // ~85.7 MB

    if (ws_size >= need) {
        char* w = (char*)d_ws;
        char* xpl  = w;              char* w1pl = xpl + XPL;
        char* w2pl = w1pl + W1PL;    char* w3pl = w2pl + W23PL;
        char* s1q  = w3pl + W23PL;   char* s2q  = s1q + SQ;

        k_decomp_x<<<1200, 256, 0, stream>>>(x, xpl);
        k_decomp_w<4,35,24><<<384, 256, 0, stream>>>(W1, w1pl, 768, 2048);
        k_decomp_w<4,35,64><<<1024, 256, 0, stream>>>(W2, w2pl, 2048, 2048);
        k_decomp_w<4,35,64><<<1024, 256, 0, stream>>>(W3, w3pl, 2048, 2048);

        k_gemm1<<<dim3(64, 25), 512, 0, stream>>>(xpl, w1pl, b1, c1, m1);
        k_scan<true><<<2048, 256, 0, stream>>>(c1, m1, s1, s1q, beta1, thr1);
        k_gemm23<<<dim3(64, 25), 512, 0, stream>>>(s1q, w2pl, b2, c2, m2);
        k_scan<true><<<2048, 256, 0, stream>>>(c2, m2, s2, s2q, beta2, thr2);
        k_gemm23<<<dim3(64, 25), 512, 0, stream>>>(s2q, w3pl, b3, c3, m3);
        k_scan<false><<<2048, 256, 0, stream>>>(c3, m3, s3, nullptr, beta3, thr3);
        k_gemm4<<<1600, 256, 0, stream>>>(s3, W4, b4, c4, m4);
        k_scan4<<<10, 256, 0, stream>>>(c4, m4, s4, beta4, thr4);
        return;
    }

    // -------- fp64 fallback (round-2 verified) --------
    const size_t NL = PT;
    const size_t WS_NEED = (3 * NL + PT4) * sizeof(double);
    const bool use64 = (d_ws != nullptr) && (ws_size >= WS_NEED);
    double* wsd = (double*)d_ws;
    double* mm1 = use64 ? wsd : nullptr;
    double* mm2 = use64 ? wsd + NL : nullptr;
    double* mm3 = use64 ? wsd + 2 * NL : nullptr;
    double* mm4 = use64 ? wsd + 3 * NL : nullptr;
    const dim3 grid(HH / BN, BB / BM);
    for (int t = 0; t < T_; ++t) {
        size_t po = (size_t)t * PT, po4 = (size_t)t * PT4;
        gemm_lif_f64<<<grid, 256, 0, stream>>>(x + (size_t)t * DIN, T_ * DIN, W1, b1,
            t ? mm1 : nullptr, t ? m1 + po - PT : nullptr, mm1,
            c1 + po, m1 + po, s1 + po, beta1, thr1, DIN, HH);
        gemm_lif_f64<<<grid, 256, 0, stream>>>(s1 + po, HH, W2, b2,
            t ? mm2 : nullptr, t ? m2 + po - PT : nullptr, mm2,
            c2 + po, m2 + po, s2 + po, beta2, thr2, HH, HH);
        gemm_lif_f64<<<grid, 256, 0, stream>>>(s2 + po, HH, W3, b3,
            t ? mm3 : nullptr, t ? m3 + po - PT : nullptr, mm3,
            c3 + po, m3 + po, s3 + po, beta3, thr3, HH, HH);
        k_fc4_lif<<<64, 256, 0, stream>>>(s3 + po, W4, b4,
            mm4 ? mm4 : (double*)d_ws, c4 + po4, m4 + po4, s4 + po4, beta4, thr4, t == 0);
    }
}